// Round 3
// baseline (1495.109 us; speedup 1.0000x reference)
//
#include <hip/hip_runtime.h>
#include <cstdint>
#include <type_traits>

namespace {

constexpr int ROWS = 256;            // B*C
constexpr int ROW_N = 65536;         // H*W
constexpr int ST = 1024;             // threads per sort block (16 waves)
constexpr int WAVES = 16;
constexpr int SEG = ROW_N / WAVES;   // 4096 elems per wave segment
constexpr int ITERS = SEG / 64;      // 64 iterations per wave per pass
constexpr size_t NTOT = (size_t)ROWS * ROW_N;

constexpr float COS_02PI = 0.80901699437494745f;  // cos(0.2*pi)
constexpr float COS_04PI = 0.30901699437494745f;  // cos(0.4*pi)

struct SortSmem {
    __align__(16) uint32_t whist[2][WAVES * 256]; // 32 KB: cur offsets / next counts
    uint32_t wtot[4];
};

__device__ __forceinline__ uint32_t fkey(float x) {
    return __float_as_uint(fabsf(x));  // monotone for non-negative floats
}

__device__ __forceinline__ uint64_t peer_mask8(uint32_t d) {
    uint64_t m = ~0ull;
#pragma unroll
    for (int b = 0; b < 8; ++b) {
        uint64_t bal = __ballot((d >> b) & 1u);
        m &= ((d >> b) & 1u) ? bal : ~bal;
    }
    return m;
}

// Stable LSD radix sort of one row, 3 x 8-bit passes on top-24 bits of |x| key.
// Wave w owns segment [w*4096, (w+1)*4096) each pass; cross-wave order via a
// once-per-pass offset table; scatter loop has NO barriers.
// src: u64 = k24<<16 | idx | sign(c)<<48 | sign(s)<<49 ; tgt: u32 full key.
// Final pass writes compact u32 into rowF (row's own retired A-slice).
template <bool IS_SRC>
__device__ void sort_row(SortSmem& sm, const float* __restrict__ raw,
                         const float* __restrict__ raw2,
                         void* bufA, void* bufB, uint32_t* __restrict__ rowF,
                         int row)
{
    using ELEM = std::conditional_t<IS_SRC, uint64_t, uint32_t>;
    const int tid = threadIdx.x;
    const int lane = tid & 63;
    const int wave = tid >> 6;
    const uint64_t lane_lt = (1ull << lane) - 1ull;

    const float* rawRow = raw + (size_t)row * ROW_N;
    const float* raw2Row = IS_SRC ? (raw2 + (size_t)row * ROW_N) : nullptr;
    ELEM* A = (ELEM*)bufA + (size_t)row * ROW_N;
    ELEM* B = (ELEM*)bufB + (size_t)row * ROW_N;

    ((uint4*)sm.whist[0])[tid] = make_uint4(0u, 0u, 0u, 0u);
    __syncthreads();

    // Prepass: per-(wave,digit0) histogram; wave reads its OWN segment (float4).
    {
        const float4* r4 = (const float4*)rawRow;
        const int base4 = wave * (SEG / 4);
#pragma unroll 4
        for (int it = 0; it < SEG / 4 / 64; ++it) {   // 16
            float4 f = r4[base4 + it * 64 + lane];
            atomicAdd(&sm.whist[0][(wave << 8) + ((fkey(f.x) >> 7) & 255u)], 1u);
            atomicAdd(&sm.whist[0][(wave << 8) + ((fkey(f.y) >> 7) & 255u)], 1u);
            atomicAdd(&sm.whist[0][(wave << 8) + ((fkey(f.z) >> 7) & 255u)], 1u);
            atomicAdd(&sm.whist[0][(wave << 8) + ((fkey(f.w) >> 7) & 255u)], 1u);
        }
    }

#pragma unroll
    for (int p = 0; p < 3; ++p) {
        const int cur = p & 1;        // 0,1,0
        const int nxt = cur ^ 1;

        __syncthreads();  // counts for this pass complete

        // Scan A: per-digit totals + exclusive scan across 256 digits
        uint32_t run = 0, inc = 0;
        if (tid < 256) {
#pragma unroll
            for (int w = 0; w < WAVES; ++w) run += sm.whist[cur][(w << 8) + tid];
            inc = run;
#pragma unroll
            for (int dlt = 1; dlt < 64; dlt <<= 1) {
                uint32_t t = __shfl_up(inc, dlt, 64);
                if (lane >= dlt) inc += t;
            }
            if (lane == 63) sm.wtot[tid >> 6] = inc;
        }
        __syncthreads();

        // zero next-pass count table (16KB, one uint4 per thread)
        ((uint4*)sm.whist[nxt])[tid] = make_uint4(0u, 0u, 0u, 0u);

        // Scan B: rewrite whist[cur] in place as (wave,digit) start offsets
        if (tid < 256) {
            uint32_t base = 0;
#pragma unroll
            for (int k = 0; k < 4; ++k) if (k < (tid >> 6)) base += sm.wtot[k];
            uint32_t excl = base + inc - run;
#pragma unroll
            for (int w = 0; w < WAVES; ++w) {
                uint32_t t = sm.whist[cur][(w << 8) + tid];
                sm.whist[cur][(w << 8) + tid] = excl;
                excl += t;
            }
        }
        __syncthreads();

        const ELEM* inb = (p == 1) ? A : B;   // p1 reads A, p2 reads B
        ELEM* outb = (p == 0) ? A : B;        // p0 writes A, p1 writes B

        auto load_elem = [&](int it) -> ELEM {
            const int gi = wave * SEG + it * 64 + lane;
            if (p == 0) {
                float cv = rawRow[gi];
                uint32_t k = fkey(cv);
                if constexpr (IS_SRC) {
                    float sv = raw2Row[gi];
                    uint64_t e = (((uint64_t)(k >> 7)) << 16) | (uint32_t)gi;
                    if (cv < 0.f) e |= 1ull << 48;
                    if (sv < 0.f) e |= 1ull << 49;
                    return e;
                } else {
                    return (ELEM)k;
                }
            }
            return inb[gi];
        };

        // Barrier-free scatter: wave-private counters + leader atomics
        ELEM v = load_elem(0);
        for (int it = 0; it < ITERS; ++it) {
            ELEM vn = (ELEM)0;
            if (it + 1 < ITERS) vn = load_elem(it + 1);   // prefetch

            uint32_t k;
            if constexpr (IS_SRC) k = (uint32_t)(v >> 16);   // k24
            else k = ((uint32_t)v) >> 7;                     // k24
            const uint32_t d = (k >> (8 * p)) & 255u;
            const uint64_t m = peer_mask8(d);
            const uint32_t rw = (uint32_t)__popcll(m & lane_lt);
            const int leader = (int)(__ffsll((unsigned long long)m) - 1);
            uint32_t cnt = 0;
            if (rw == 0u)
                cnt = atomicAdd(&sm.whist[cur][(wave << 8) + d],
                                (uint32_t)__popcll(m));
            cnt = (uint32_t)__shfl((int)cnt, leader, 64);
            const uint32_t off = cnt + rw;

            if (p < 2) {
                const uint32_t nd = (k >> (8 * (p + 1))) & 255u;
                atomicAdd(&sm.whist[nxt][((off >> 12) << 8) + nd], 1u);
                outb[off] = v;
            } else {
                if constexpr (IS_SRC)
                    rowF[off] = (uint32_t)(v & 0xFFFFull) |
                                (((uint32_t)(v >> 48)) << 16);
                else
                    rowF[off] = (uint32_t)v;   // exact |style| bits
            }
            v = vn;
        }
    }
}

__device__ __forceinline__ float detail_one(float c, float s) {
    const float f = (c < 0.f) ? ((s < 0.f) ? -1.f : COS_04PI)
                              : ((s < 0.f) ? -COS_04PI : 1.f);
    return (0.4f * fabsf(c) + 0.6f * fabsf(s)) * f;
}

} // namespace

__global__ __launch_bounds__(ST, 8)
void sort_merged(const float* __restrict__ ca, const float* __restrict__ sa,
                 void* srcA, void* srcB, void* tgtA, void* tgtB)
{
    __shared__ SortSmem sm;
    const int b = blockIdx.x;
    const int row = b >> 1;
    if ((b & 1) == 0) {
        // src final u32 goes into the first half of this row's own A slice
        uint32_t* rowF = (uint32_t*)((uint64_t*)srcA + (size_t)row * ROW_N);
        sort_row<true>(sm, ca, sa, srcA, srcB, rowF - (size_t)row * ROW_N, row);
        // note: sort_row indexes rowF internally without row offset; pass base
    } else {
        // tgt final u32 overwrites this row's own tgtA slice (same layout)
        sort_row<false>(sm, sa, nullptr, tgtA, tgtB, (uint32_t*)tgtA + (size_t)row * ROW_N - (size_t)row * ROW_N + (size_t)row * ROW_N - (size_t)row * ROW_N, row);
    }
}

// (rowF plumbing done cleanly below via wrappers)
__global__ __launch_bounds__(ST, 8)
void sort_merged2(const float* __restrict__ ca, const float* __restrict__ sa,
                  void* srcA, void* srcB, void* tgtA, void* tgtB)
{
    __shared__ SortSmem sm;
    const int b = blockIdx.x;
    const int row = b >> 1;
    if ((b & 1) == 0) {
        uint32_t* rowF = (uint32_t*)((uint64_t*)srcA + (size_t)row * ROW_N);
        sort_row<true>(sm, ca, sa, srcA, srcB, rowF, row);
    } else {
        uint32_t* rowF = (uint32_t*)tgtA + (size_t)row * ROW_N;
        sort_row<false>(sm, sa, nullptr, tgtA, tgtB, rowF, row);
    }
}

// out0[row, idx] = t_sorted[row, k] * cos(0.8*ph(c) + 0.2*ph(s))
// srcF rows live at stride 131072 u32 (first half of each row's u64 A slice);
// tgtF is a flat [ROWS][ROW_N] u32 array.
__global__ __launch_bounds__(256)
void approx_finalize(const uint32_t* __restrict__ srcF,
                     const uint32_t* __restrict__ tgtF,
                     float* __restrict__ out0)
{
    const size_t kk = (size_t)blockIdx.x * blockDim.x + threadIdx.x;
    const size_t row = kk >> 16;
    const uint32_t kl = (uint32_t)(kk & 65535u);
    const uint32_t v = srcF[(row << 17) | kl];
    const size_t j = (row << 16) | (v & 0xFFFFu);
    const float t = __uint_as_float(tgtF[kk]);
    const uint32_t cneg = (v >> 16) & 1u;
    const uint32_t sneg = (v >> 17) & 1u;
    const float f = cneg ? (sneg ? -1.f : -COS_02PI)
                         : (sneg ? COS_02PI : 1.f);
    out0[j] = t * f;
}

__global__ __launch_bounds__(256)
void details_kernel(const float4* __restrict__ ch, const float4* __restrict__ sh,
                    const float4* __restrict__ cv, const float4* __restrict__ sv,
                    const float4* __restrict__ cd, const float4* __restrict__ sd,
                    float4* __restrict__ oh, float4* __restrict__ ov,
                    float4* __restrict__ od)
{
    const size_t i = (size_t)blockIdx.x * blockDim.x + threadIdx.x;
    float4 a, b, r;
    a = ch[i]; b = sh[i];
    r.x = detail_one(a.x, b.x); r.y = detail_one(a.y, b.y);
    r.z = detail_one(a.z, b.z); r.w = detail_one(a.w, b.w);
    oh[i] = r;
    a = cv[i]; b = sv[i];
    r.x = detail_one(a.x, b.x); r.y = detail_one(a.y, b.y);
    r.z = detail_one(a.z, b.z); r.w = detail_one(a.w, b.w);
    ov[i] = r;
    a = cd[i]; b = sd[i];
    r.x = detail_one(a.x, b.x); r.y = detail_one(a.y, b.y);
    r.z = detail_one(a.z, b.z); r.w = detail_one(a.w, b.w);
    od[i] = r;
}

extern "C" void kernel_launch(void* const* d_in, const int* in_sizes, int n_in,
                              void* d_out, int out_size, void* d_ws, size_t ws_size,
                              hipStream_t stream)
{
    (void)in_sizes; (void)n_in; (void)out_size; (void)ws_size;
    const float* ca = (const float*)d_in[0];
    const float* ch = (const float*)d_in[1];
    const float* cv = (const float*)d_in[2];
    const float* cd = (const float*)d_in[3];
    const float* sa = (const float*)d_in[4];
    const float* sh = (const float*)d_in[5];
    const float* sv = (const float*)d_in[6];
    const float* sd = (const float*)d_in[7];

    float* out = (float*)d_out;
    float* out_a = out;
    float* out_h = out + NTOT;
    float* out_v = out + 2 * NTOT;
    float* out_d = out + 3 * NTOT;

    // Scratch (needs ws >= 201 MB, proven available by prior rounds):
    //  srcA: ws[0,134MB)  u64 ping; pass2 writes compact u32 into each row's
    //        own retired A slice (stride 131072 u32 per row)
    //  tgtA: ws[134,201MB) u32 ping; pass2 overwrites own slice (flat u32)
    //  srcB: out_h..out_v (134MB u64 pong), tgtB: out_d (67MB u32 pong)
    // finalize reads ws only; details then freely overwrites out_h/v/d.
    uint64_t* srcA = (uint64_t*)d_ws;
    uint64_t* srcB = (uint64_t*)out_h;
    uint32_t* tgtA = (uint32_t*)((char*)d_ws + NTOT * 8);
    uint32_t* tgtB = (uint32_t*)out_d;

    sort_merged2<<<2 * ROWS, ST, 0, stream>>>(ca, sa, srcA, srcB, tgtA, tgtB);

    approx_finalize<<<(int)(NTOT / 256), 256, 0, stream>>>(
        (const uint32_t*)srcA, (const uint32_t*)tgtA, out_a);

    details_kernel<<<(int)(NTOT / 4 / 256), 256, 0, stream>>>(
        (const float4*)ch, (const float4*)sh,
        (const float4*)cv, (const float4*)sv,
        (const float4*)cd, (const float4*)sd,
        (float4*)out_h, (float4*)out_v, (float4*)out_d);
}